// Round 5
// baseline (240.156 us; speedup 1.0000x reference)
//
#include <hip/hip_runtime.h>
#include <hip/hip_bf16.h>

#define C_IN 64
#define C_OUT 8
#define IMG 128
#define HW (IMG * IMG)
#define BATCH 32
#define K_STEPS 8

// ---------------------------------------------------------------------------
// Kernel A: 1x1 conv + gate + bias + coordinate channels.
// feat layout: [B][HW][C_OUT] (pixel-major, 32B per pixel) in workspace.
// ---------------------------------------------------------------------------
__global__ __launch_bounds__(256) void semiconv_kernel(
    const float* __restrict__ x,      // [B][C_IN][HW]
    const float* __restrict__ w,      // [C_OUT][C_IN]
    const float* __restrict__ bias,   // [C_OUT]
    const float* __restrict__ gate_p, // scalar
    float* __restrict__ feat)         // [B][HW][C_OUT]
{
    __shared__ float sw[C_OUT * C_IN];
    const int tid = threadIdx.x;
    for (int i = tid; i < C_OUT * C_IN; i += 256) sw[i] = w[i];
    __syncthreads();

    // 512 blocks; 16 blocks per batch; each thread does 4 consecutive pixels.
    const int b  = blockIdx.x >> 4;
    const int p4 = (((blockIdx.x & 15) * 256) + tid) * 4;

    const float gate = *gate_p;
    const float* xb = x + (long long)b * C_IN * HW + p4;

    float acc[C_OUT][4];
    #pragma unroll
    for (int o = 0; o < C_OUT; ++o) {
        const float bv = bias[o];
        #pragma unroll
        for (int j = 0; j < 4; ++j) acc[o][j] = bv;
    }

    for (int c = 0; c < C_IN; ++c) {
        const float4 xv = *(const float4*)(xb + c * HW);
        const float xs[4] = {xv.x, xv.y, xv.z, xv.w};
        #pragma unroll
        for (int o = 0; o < C_OUT; ++o) {
            const float wv = sw[o * C_IN + c];
            #pragma unroll
            for (int j = 0; j < 4; ++j) acc[o][j] = fmaf(wv, xs[j], acc[o][j]);
        }
    }

    const int row  = p4 / IMG;
    const int col0 = p4 % IMG;   // 4 consecutive pixels stay in one row (128 % 4 == 0)
    const float step = 2.0f / (IMG - 1);
    const float g1 = -1.0f + step * (float)row;

    float* dst = feat + ((long long)b * HW + p4) * C_OUT;
    #pragma unroll
    for (int j = 0; j < 4; ++j) {
        float o0 = gate * acc[0][j];
        float o1 = gate * acc[1][j];
        float o2 = gate * acc[2][j];
        float o3 = gate * acc[3][j];
        float o4 = gate * acc[4][j];
        float o5 = gate * acc[5][j];
        float o6 = gate * acc[6][j] + g1;
        float o7 = gate * acc[7][j] + (-1.0f + step * (float)(col0 + j));
        float4 v0 = make_float4(o0, o1, o2, o3);
        float4 v1 = make_float4(o4, o5, o6, o7);
        *(float4*)(dst + j * C_OUT)     = v0;
        *(float4*)(dst + j * C_OUT + 4) = v1;
    }
}

// ---------------------------------------------------------------------------
// Kernel B: persistent stick-breaking. One block (1024 threads) per batch.
// Argmax protocol is race-free BY CONSTRUCTION:
//   - parity double-buffered LDS candidate slots (iteration s uses slot s&1)
//   - xor-butterfly wave reduce (all lanes converge to same max/min-index)
//   - every thread redundantly reduces the 16 wave candidates (no sBest
//     broadcast variable, purely uniform LDS reads)
//   - barrier after candidate writes + barrier at end of each step
// ---------------------------------------------------------------------------
#define NTHREADS 1024
#define NWAVES (NTHREADS / 64)
#define PPT (HW / NTHREADS)  // 16

__global__ __launch_bounds__(NTHREADS) void stick_kernel(
    const float* __restrict__ feat,        // [B][HW][C_OUT]
    const float* __restrict__ rand_pixel,  // [B][HW]
    const float* __restrict__ log_sigma_p, // scalar
    float* __restrict__ masks,             // [B][K][HW]
    float* __restrict__ scopes)            // [B][K][HW]
{
    const int b    = blockIdx.x;
    const int tid  = threadIdx.x;
    const int lane = tid & 63;
    const int wid  = tid >> 6;

    const float inv_sigma = expf(-(*log_sigma_p));  // 1/sigma

    const float* fb = feat + (long long)b * HW * C_OUT;
    const float* rb = rand_pixel + (long long)b * HW;
    float* mb = masks  + (long long)b * (K_STEPS * HW);
    float* sb = scopes + (long long)b * (K_STEPS * HW);

    float ls[PPT];
    float rp[PPT];
    #pragma unroll
    for (int i = 0; i < PPT; ++i) {
        const int p = tid + i * NTHREADS;
        ls[i] = 0.0f;
        rp[i] = rb[p];
        sb[p] = 0.0f;  // log_scopes[:,0] = 0
    }

    __shared__ float swv[2][NWAVES];
    __shared__ int   swi[2][NWAVES];

    for (int s = 0; s < K_STEPS - 1; ++s) {
        const int par = s & 1;

        // ---- per-thread argmax of rand * exp(log_scope); first-occurrence ----
        float bv = -1.0f;
        int   bi = 0x7fffffff;
        #pragma unroll
        for (int i = 0; i < PPT; ++i) {
            const float v = rp[i] * expf(ls[i]);
            const int p = tid + i * NTHREADS;
            if (v > bv) { bv = v; bi = p; }  // strict > keeps lowest p on ties
        }
        // ---- xor-butterfly wave reduce: all lanes get (max, min-index) ----
        #pragma unroll
        for (int off = 1; off < 64; off <<= 1) {
            const float ov = __shfl_xor(bv, off);
            const int   oi = __shfl_xor(bi, off);
            if (ov > bv || (ov == bv && oi < bi)) { bv = ov; bi = oi; }
        }
        if (lane == 0) { swv[par][wid] = bv; swi[par][wid] = bi; }
        __syncthreads();

        // ---- redundant block reduce in every thread (uniform LDS reads) ----
        float v0 = swv[par][0];
        int   seedIdx = swi[par][0];
        #pragma unroll
        for (int wv = 1; wv < NWAVES; ++wv) {
            const float vv = swv[par][wv];
            const int   ii = swi[par][wv];
            if (vv > v0 || (vv == v0 && ii < seedIdx)) { v0 = vv; seedIdx = ii; }
        }

        // seed features (uniform address -> broadcast load, L2-hot)
        const float4 s0 = *(const float4*)(fb + (long long)seedIdx * C_OUT);
        const float4 s1 = *(const float4*)(fb + (long long)seedIdx * C_OUT + 4);

        #pragma unroll
        for (int i = 0; i < PPT; ++i) {
            const int p = tid + i * NTHREADS;
            const float4 f0 = *(const float4*)(fb + (long long)p * C_OUT);
            const float4 f1 = *(const float4*)(fb + (long long)p * C_OUT + 4);
            float d, sq = 0.0f;
            d = f0.x - s0.x; sq += d * d;
            d = f0.y - s0.y; sq += d * d;
            d = f0.z - s0.z; sq += d * d;
            d = f0.w - s0.w; sq += d * d;
            d = f1.x - s1.x; sq += d * d;
            d = f1.y - s1.y; sq += d * d;
            d = f1.z - s1.z; sq += d * d;
            d = f1.w - s1.w; sq += d * d;
            float alpha = expf(-sq * inv_sigma);
            alpha = fminf(fmaxf(alpha, 0.01f), 0.99f);  // straight-through clamp (fwd)
            mb[s * HW + p] = ls[i] + logf(alpha);
            ls[i] += log1pf(-alpha);
            sb[(s + 1) * HW + p] = ls[i];
        }
        __syncthreads();  // close read -> next-iteration-write window
    }

    // last mask = final scope
    #pragma unroll
    for (int i = 0; i < PPT; ++i) {
        const int p = tid + i * NTHREADS;
        mb[(K_STEPS - 1) * HW + p] = ls[i];
    }
}

extern "C" void kernel_launch(void* const* d_in, const int* in_sizes, int n_in,
                              void* d_out, int out_size, void* d_ws, size_t ws_size,
                              hipStream_t stream) {
    const float* x          = (const float*)d_in[0];  // [32,64,128,128]
    const float* rand_pixel = (const float*)d_in[1];  // [32,1,128,128]
    const float* conv_w     = (const float*)d_in[2];  // [8,64]
    const float* conv_b     = (const float*)d_in[3];  // [8]
    const float* gate       = (const float*)d_in[4];  // scalar
    const float* log_sigma  = (const float*)d_in[5];  // scalar

    float* masks  = (float*)d_out;                          // [32,8,128,128]
    float* scopes = masks + (long long)BATCH * K_STEPS * HW;

    float* feat = (float*)d_ws;  // [32][16384][8] = 16.8 MB

    semiconv_kernel<<<(BATCH * HW) / (256 * 4), 256, 0, stream>>>(
        x, conv_w, conv_b, gate, feat);

    stick_kernel<<<BATCH, NTHREADS, 0, stream>>>(
        feat, rand_pixel, log_sigma, masks, scopes);
}

// Round 6
// 98.487 us; speedup vs baseline: 2.4385x; 2.4385x over previous
//
#include <hip/hip_runtime.h>
#include <hip/hip_bf16.h>

#define C_IN 64
#define C_OUT 8
#define IMG 128
#define HW (IMG * IMG)
#define BATCH 32
#define K_STEPS 8

#define FEAT_BYTES ((size_t)BATCH * HW * C_OUT * 4)   // 16,777,216
#define BLK_PER_B 8
#define NFLAGS ((K_STEPS - 1) * BATCH * BLK_PER_B)    // 1792 u64 words

// ---------------------------------------------------------------------------
// Kernel A: 1x1 conv + gate + bias + coordinate channels.
// feat layout: [B][HW][C_OUT] (pixel-major, 32B per pixel) in workspace.
// Block 0 additionally zeroes the cross-block sync flags for kernel B
// (stream order guarantees visibility; re-zeroed every launch => replay-safe).
// ---------------------------------------------------------------------------
__global__ __launch_bounds__(256) void semiconv_kernel(
    const float* __restrict__ x,      // [B][C_IN][HW]
    const float* __restrict__ w,      // [C_OUT][C_IN]
    const float* __restrict__ bias,   // [C_OUT]
    const float* __restrict__ gate_p, // scalar
    float* __restrict__ feat,         // [B][HW][C_OUT]
    unsigned long long* __restrict__ flags)
{
    __shared__ float sw[C_OUT * C_IN];
    const int tid = threadIdx.x;
    if (blockIdx.x == 0) {
        for (int k = tid; k < NFLAGS; k += 256) flags[k] = 0ULL;
    }
    for (int i = tid; i < C_OUT * C_IN; i += 256) sw[i] = w[i];
    __syncthreads();

    const int b  = blockIdx.x >> 4;
    const int p4 = (((blockIdx.x & 15) * 256) + tid) * 4;

    const float gate = *gate_p;
    const float* xb = x + (long long)b * C_IN * HW + p4;

    float acc[C_OUT][4];
    #pragma unroll
    for (int o = 0; o < C_OUT; ++o) {
        const float bv = bias[o];
        #pragma unroll
        for (int j = 0; j < 4; ++j) acc[o][j] = bv;
    }

    for (int c = 0; c < C_IN; ++c) {
        const float4 xv = *(const float4*)(xb + c * HW);
        const float xs[4] = {xv.x, xv.y, xv.z, xv.w};
        #pragma unroll
        for (int o = 0; o < C_OUT; ++o) {
            const float wv = sw[o * C_IN + c];
            #pragma unroll
            for (int j = 0; j < 4; ++j) acc[o][j] = fmaf(wv, xs[j], acc[o][j]);
        }
    }

    const int row  = p4 / IMG;
    const int col0 = p4 % IMG;
    const float step = 2.0f / (IMG - 1);
    const float g1 = -1.0f + step * (float)row;

    float* dst = feat + ((long long)b * HW + p4) * C_OUT;
    #pragma unroll
    for (int j = 0; j < 4; ++j) {
        float o0 = gate * acc[0][j];
        float o1 = gate * acc[1][j];
        float o2 = gate * acc[2][j];
        float o3 = gate * acc[3][j];
        float o4 = gate * acc[4][j];
        float o5 = gate * acc[5][j];
        float o6 = gate * acc[6][j] + g1;
        float o7 = gate * acc[7][j] + (-1.0f + step * (float)(col0 + j));
        *(float4*)(dst + j * C_OUT)     = make_float4(o0, o1, o2, o3);
        *(float4*)(dst + j * C_OUT + 4) = make_float4(o4, o5, o6, o7);
    }
}

// ---------------------------------------------------------------------------
// Kernel B: stick-breaking, 8 blocks per batch (grid 256 = 1 block/CU).
//  - per-thread feat chunk held in registers (2 px x 8 ch)
//  - per-step cross-block argmax: block partial packed (val_bits<<32)|(idx+1),
//    device-scope release store to per-(step,batch,block) flag slot; wave 0
//    lanes 0..7 acquire-poll all 8 slots, reduce, broadcast via LDS.
//  - slots are write-once per launch (per-step indexed); zeroed by kernel A.
//  - deadlock-free: 1024-thread blocks => VGPR<=128 => >=1 block/CU capacity
//    => all 256 blocks resident.
//  - alpha / log1pf / expf(ls) bitwise identical to the validated r5 kernel;
//    log(alpha) replaced by -t / clamp constants (output-only ~1e-7 delta).
// ---------------------------------------------------------------------------
#define NT 1024
#define CHUNK (HW / BLK_PER_B)   // 2048
#define PPT (CHUNK / NT)         // 2

__global__ __launch_bounds__(NT) void stick_kernel(
    const float* __restrict__ feat,        // [B][HW][C_OUT]
    const float* __restrict__ rand_pixel,  // [B][HW]
    const float* __restrict__ log_sigma_p, // scalar
    float* __restrict__ masks,             // [B][K][HW]
    float* __restrict__ scopes,            // [B][K][HW]
    unsigned long long* __restrict__ flags)// [K-1][B][BLK_PER_B]
{
    // XCD swizzle: batch b's 8 blocks share blockIdx%8 -> same XCD (perf only).
    const int b   = blockIdx.x & 31;
    const int blk = blockIdx.x >> 5;
    const int tid  = threadIdx.x;
    const int lane = tid & 63;
    const int wid  = tid >> 6;          // 0..15

    const float inv_sigma = expf(-(*log_sigma_p));

    const float* fb = feat + (size_t)b * HW * C_OUT;
    const float* rb = rand_pixel + (size_t)b * HW;
    float* mb = masks  + (size_t)b * (K_STEPS * HW);
    float* sb = scopes + (size_t)b * (K_STEPS * HW);

    const int base = blk * CHUNK;

    float4 f0[PPT], f1[PPT];
    float rp[PPT], ls[PPT];
    #pragma unroll
    for (int k = 0; k < PPT; ++k) {
        const int p = base + k * NT + tid;
        f0[k] = *(const float4*)(fb + (size_t)p * C_OUT);
        f1[k] = *(const float4*)(fb + (size_t)p * C_OUT + 4);
        rp[k] = rb[p];
        ls[k] = 0.0f;
        sb[p] = 0.0f;                    // log_scopes[:,0] = 0
    }

    __shared__ float swv[2][16];
    __shared__ int   swi[2][16];
    __shared__ int   sSeed[2];

    for (int s = 0; s < K_STEPS - 1; ++s) {
        const int par = s & 1;

        // ---- per-thread argmax of rand * exp(log_scope); first occurrence ----
        float bv = -1.0f;
        int   bi = 0x7fffffff;
        #pragma unroll
        for (int k = 0; k < PPT; ++k) {
            const float v = rp[k] * expf(ls[k]);
            if (v > bv) { bv = v; bi = base + k * NT + tid; }  // ascending idx
        }
        // ---- xor-butterfly wave reduce (max, tie -> min idx) ----
        #pragma unroll
        for (int off = 1; off < 64; off <<= 1) {
            const float ov = __shfl_xor(bv, off);
            const int   oi = __shfl_xor(bi, off);
            if (ov > bv || (ov == bv && oi < bi)) { bv = ov; bi = oi; }
        }
        if (lane == 0) { swv[par][wid] = bv; swi[par][wid] = bi; }
        __syncthreads();

        // ---- wave 0: block reduce, publish, poll peers, global reduce ----
        if (wid == 0) {
            float v = (lane < 16) ? swv[par][lane] : -1.0f;
            int   ix = (lane < 16) ? swi[par][lane] : 0x7fffffff;
            #pragma unroll
            for (int off = 1; off < 16; off <<= 1) {
                const float ov = __shfl_xor(v, off);
                const int   oi = __shfl_xor(ix, off);
                if (ov > v || (ov == v && oi < ix)) { v = ov; ix = oi; }
            }
            if (lane == 0) {
                const unsigned long long pk =
                    ((unsigned long long)__float_as_uint(v) << 32) |
                    (unsigned long long)(unsigned int)(ix + 1);
                __hip_atomic_store(&flags[(s * BATCH + b) * BLK_PER_B + blk], pk,
                                   __ATOMIC_RELEASE, __HIP_MEMORY_SCOPE_AGENT);
            }
            float gv = -1.0f;
            int   gi = 0x7fffffff;
            if (lane < BLK_PER_B) {
                unsigned long long got;
                do {
                    got = __hip_atomic_load(
                        &flags[(s * BATCH + b) * BLK_PER_B + lane],
                        __ATOMIC_ACQUIRE, __HIP_MEMORY_SCOPE_AGENT);
                } while (got == 0ULL);
                gv = __uint_as_float((unsigned int)(got >> 32));
                gi = (int)(unsigned int)(got & 0xffffffffULL) - 1;
            }
            #pragma unroll
            for (int off = 1; off < 8; off <<= 1) {
                const float ov = __shfl_xor(gv, off);
                const int   oi = __shfl_xor(gi, off);
                if (ov > gv || (ov == gv && oi < gi)) { gv = ov; gi = oi; }
            }
            if (lane == 0) sSeed[par] = gi;
        }
        __syncthreads();
        const int seedIdx = sSeed[par];

        // seed features (uniform address -> broadcast, L2-local via swizzle)
        const float4 s0 = *(const float4*)(fb + (size_t)seedIdx * C_OUT);
        const float4 s1 = *(const float4*)(fb + (size_t)seedIdx * C_OUT + 4);

        #pragma unroll
        for (int k = 0; k < PPT; ++k) {
            const int p = base + k * NT + tid;
            float d, sq = 0.0f;
            d = f0[k].x - s0.x; sq += d * d;
            d = f0[k].y - s0.y; sq += d * d;
            d = f0[k].z - s0.z; sq += d * d;
            d = f0[k].w - s0.w; sq += d * d;
            d = f1[k].x - s1.x; sq += d * d;
            d = f1[k].y - s1.y; sq += d * d;
            d = f1[k].z - s1.z; sq += d * d;
            d = f1[k].w - s1.w; sq += d * d;
            const float t = sq * inv_sigma;
            float alpha = expf(-t);
            float log_a;
            if (alpha >= 0.99f)      { alpha = 0.99f; log_a = -0.010050336f; } // ln(0.99)
            else if (alpha <= 0.01f) { alpha = 0.01f; log_a = -4.6051702f;  }  // ln(0.01)
            else                     { log_a = -t; }
            mb[s * HW + p] = ls[k] + log_a;
            ls[k] += log1pf(-alpha);
            sb[(s + 1) * HW + p] = ls[k];
        }
        // LDS race-freedom: parity double-buffer on swv/swi/sSeed + the two
        // barriers above separate same-slot accesses two steps apart.
    }

    #pragma unroll
    for (int k = 0; k < PPT; ++k) {
        const int p = base + k * NT + tid;
        mb[(K_STEPS - 1) * HW + p] = ls[k];  // last mask = final scope
    }
}

extern "C" void kernel_launch(void* const* d_in, const int* in_sizes, int n_in,
                              void* d_out, int out_size, void* d_ws, size_t ws_size,
                              hipStream_t stream) {
    const float* x          = (const float*)d_in[0];  // [32,64,128,128]
    const float* rand_pixel = (const float*)d_in[1];  // [32,1,128,128]
    const float* conv_w     = (const float*)d_in[2];  // [8,64]
    const float* conv_b     = (const float*)d_in[3];  // [8]
    const float* gate       = (const float*)d_in[4];  // scalar
    const float* log_sigma  = (const float*)d_in[5];  // scalar

    float* masks  = (float*)d_out;                          // [32,8,128,128]
    float* scopes = masks + (long long)BATCH * K_STEPS * HW;

    float* feat = (float*)d_ws;  // [32][16384][8] = 16.8 MB
    unsigned long long* flags =
        (unsigned long long*)((char*)d_ws + FEAT_BYTES);     // 14 KB

    semiconv_kernel<<<(BATCH * HW) / (256 * 4), 256, 0, stream>>>(
        x, conv_w, conv_b, gate, feat, flags);

    stick_kernel<<<BATCH * BLK_PER_B, NT, 0, stream>>>(
        feat, rand_pixel, log_sigma, masks, scopes, flags);
}

// Round 7
// 73.748 us; speedup vs baseline: 3.2565x; 1.3355x over previous
//
#include <hip/hip_runtime.h>
#include <hip/hip_bf16.h>

#define C_IN 64
#define C_OUT 8
#define IMG 128
#define HW (IMG * IMG)
#define BATCH 32
#define K_STEPS 8

#define FEAT_BYTES ((size_t)BATCH * HW * C_OUT * 4)   // 16,777,216
#define BLK_PER_B 8
#define NFLAGS ((K_STEPS - 1) * BATCH * BLK_PER_B)    // 1792 u64 words

// ---------------------------------------------------------------------------
// Kernel A: 1x1 conv + gate + bias + coordinate channels.
// feat layout: [B][HW][C_OUT] (pixel-major, 32B per pixel) in workspace.
// Block 0 additionally zeroes the cross-block sync flags for kernel B
// (stream order guarantees visibility; re-zeroed every launch => replay-safe).
// ---------------------------------------------------------------------------
__global__ __launch_bounds__(256) void semiconv_kernel(
    const float* __restrict__ x,      // [B][C_IN][HW]
    const float* __restrict__ w,      // [C_OUT][C_IN]
    const float* __restrict__ bias,   // [C_OUT]
    const float* __restrict__ gate_p, // scalar
    float* __restrict__ feat,         // [B][HW][C_OUT]
    unsigned long long* __restrict__ flags)
{
    __shared__ float sw[C_OUT * C_IN];
    const int tid = threadIdx.x;
    if (blockIdx.x == 0) {
        for (int k = tid; k < NFLAGS; k += 256) flags[k] = 0ULL;
    }
    for (int i = tid; i < C_OUT * C_IN; i += 256) sw[i] = w[i];
    __syncthreads();

    const int b  = blockIdx.x >> 4;
    const int p4 = (((blockIdx.x & 15) * 256) + tid) * 4;

    const float gate = *gate_p;
    const float* xb = x + (long long)b * C_IN * HW + p4;

    float acc[C_OUT][4];
    #pragma unroll
    for (int o = 0; o < C_OUT; ++o) {
        const float bv = bias[o];
        #pragma unroll
        for (int j = 0; j < 4; ++j) acc[o][j] = bv;
    }

    for (int c = 0; c < C_IN; ++c) {
        const float4 xv = *(const float4*)(xb + c * HW);
        const float xs[4] = {xv.x, xv.y, xv.z, xv.w};
        #pragma unroll
        for (int o = 0; o < C_OUT; ++o) {
            const float wv = sw[o * C_IN + c];
            #pragma unroll
            for (int j = 0; j < 4; ++j) acc[o][j] = fmaf(wv, xs[j], acc[o][j]);
        }
    }

    const int row  = p4 / IMG;
    const int col0 = p4 % IMG;
    const float step = 2.0f / (IMG - 1);
    const float g1 = -1.0f + step * (float)row;

    float* dst = feat + ((long long)b * HW + p4) * C_OUT;
    #pragma unroll
    for (int j = 0; j < 4; ++j) {
        float o0 = gate * acc[0][j];
        float o1 = gate * acc[1][j];
        float o2 = gate * acc[2][j];
        float o3 = gate * acc[3][j];
        float o4 = gate * acc[4][j];
        float o5 = gate * acc[5][j];
        float o6 = gate * acc[6][j] + g1;
        float o7 = gate * acc[7][j] + (-1.0f + step * (float)(col0 + j));
        *(float4*)(dst + j * C_OUT)     = make_float4(o0, o1, o2, o3);
        *(float4*)(dst + j * C_OUT + 4) = make_float4(o4, o5, o6, o7);
    }
}

// ---------------------------------------------------------------------------
// Kernel B: stick-breaking, 8 blocks per batch (grid 256 = 1 block/CU).
//  - per-thread feat chunk held in registers (2 px x 8 ch)
//  - per-step cross-block argmax: block partial packed (val_bits<<32)|(idx+1),
//    RELAXED agent-scope atomic store to per-(step,batch,block) flag slot;
//    wave 0 lanes 0..7 RELAXED-poll all 8 slots, reduce, broadcast via LDS.
//    Relaxed is sufficient: the (val,idx) payload travels INSIDE the atomic
//    word; no other cross-block data exists (feat is from the previous
//    kernel, masks/scopes are block-private). Dropping acquire/release
//    removes per-iteration buffer_inv / writeback fences from the spin loop.
//  - slots are write-once per launch (per-step indexed); zeroed by kernel A.
//  - deadlock-free: 1024-thread blocks => VGPR<=128 => >=1 block/CU capacity
//    => all 256 blocks resident.
//  - alpha / log1pf / expf(ls) bitwise identical to the validated r5/r6 path.
// ---------------------------------------------------------------------------
#define NT 1024
#define CHUNK (HW / BLK_PER_B)   // 2048
#define PPT (CHUNK / NT)         // 2

__global__ __launch_bounds__(NT) void stick_kernel(
    const float* __restrict__ feat,        // [B][HW][C_OUT]
    const float* __restrict__ rand_pixel,  // [B][HW]
    const float* __restrict__ log_sigma_p, // scalar
    float* __restrict__ masks,             // [B][K][HW]
    float* __restrict__ scopes,            // [B][K][HW]
    unsigned long long* __restrict__ flags)// [K-1][B][BLK_PER_B]
{
    // XCD swizzle: batch b's 8 blocks share blockIdx%8 -> same XCD (perf only).
    const int b   = blockIdx.x & 31;
    const int blk = blockIdx.x >> 5;
    const int tid  = threadIdx.x;
    const int lane = tid & 63;
    const int wid  = tid >> 6;          // 0..15

    const float inv_sigma = expf(-(*log_sigma_p));

    const float* fb = feat + (size_t)b * HW * C_OUT;
    const float* rb = rand_pixel + (size_t)b * HW;
    float* mb = masks  + (size_t)b * (K_STEPS * HW);
    float* sb = scopes + (size_t)b * (K_STEPS * HW);

    const int base = blk * CHUNK;

    float4 f0[PPT], f1[PPT];
    float rp[PPT], ls[PPT];
    #pragma unroll
    for (int k = 0; k < PPT; ++k) {
        const int p = base + k * NT + tid;
        f0[k] = *(const float4*)(fb + (size_t)p * C_OUT);
        f1[k] = *(const float4*)(fb + (size_t)p * C_OUT + 4);
        rp[k] = rb[p];
        ls[k] = 0.0f;
        sb[p] = 0.0f;                    // log_scopes[:,0] = 0
    }

    __shared__ float swv[2][16];
    __shared__ int   swi[2][16];
    __shared__ int   sSeed[2];

    for (int s = 0; s < K_STEPS - 1; ++s) {
        const int par = s & 1;

        // ---- per-thread argmax of rand * exp(log_scope); first occurrence ----
        float bv = -1.0f;
        int   bi = 0x7fffffff;
        #pragma unroll
        for (int k = 0; k < PPT; ++k) {
            const float v = rp[k] * expf(ls[k]);
            if (v > bv) { bv = v; bi = base + k * NT + tid; }  // ascending idx
        }
        // ---- xor-butterfly wave reduce (max, tie -> min idx) ----
        #pragma unroll
        for (int off = 1; off < 64; off <<= 1) {
            const float ov = __shfl_xor(bv, off);
            const int   oi = __shfl_xor(bi, off);
            if (ov > bv || (ov == bv && oi < bi)) { bv = ov; bi = oi; }
        }
        if (lane == 0) { swv[par][wid] = bv; swi[par][wid] = bi; }
        __syncthreads();

        // ---- wave 0: block reduce, publish, poll peers, global reduce ----
        if (wid == 0) {
            float v = (lane < 16) ? swv[par][lane] : -1.0f;
            int   ix = (lane < 16) ? swi[par][lane] : 0x7fffffff;
            #pragma unroll
            for (int off = 1; off < 16; off <<= 1) {
                const float ov = __shfl_xor(v, off);
                const int   oi = __shfl_xor(ix, off);
                if (ov > v || (ov == v && oi < ix)) { v = ov; ix = oi; }
            }
            if (lane == 0) {
                const unsigned long long pk =
                    ((unsigned long long)__float_as_uint(v) << 32) |
                    (unsigned long long)(unsigned int)(ix + 1);
                __hip_atomic_store(&flags[(s * BATCH + b) * BLK_PER_B + blk], pk,
                                   __ATOMIC_RELAXED, __HIP_MEMORY_SCOPE_AGENT);
            }
            float gv = -1.0f;
            int   gi = 0x7fffffff;
            if (lane < BLK_PER_B) {
                unsigned long long got;
                do {
                    got = __hip_atomic_load(
                        &flags[(s * BATCH + b) * BLK_PER_B + lane],
                        __ATOMIC_RELAXED, __HIP_MEMORY_SCOPE_AGENT);
                } while (got == 0ULL);
                gv = __uint_as_float((unsigned int)(got >> 32));
                gi = (int)(unsigned int)(got & 0xffffffffULL) - 1;
            }
            #pragma unroll
            for (int off = 1; off < 8; off <<= 1) {
                const float ov = __shfl_xor(gv, off);
                const int   oi = __shfl_xor(gi, off);
                if (ov > gv || (ov == gv && oi < gi)) { gv = ov; gi = oi; }
            }
            if (lane == 0) sSeed[par] = gi;
        }
        __syncthreads();
        const int seedIdx = sSeed[par];

        // seed features (uniform address -> broadcast, L2-local via swizzle)
        const float4 s0 = *(const float4*)(fb + (size_t)seedIdx * C_OUT);
        const float4 s1 = *(const float4*)(fb + (size_t)seedIdx * C_OUT + 4);

        #pragma unroll
        for (int k = 0; k < PPT; ++k) {
            const int p = base + k * NT + tid;
            float d, sq = 0.0f;
            d = f0[k].x - s0.x; sq += d * d;
            d = f0[k].y - s0.y; sq += d * d;
            d = f0[k].z - s0.z; sq += d * d;
            d = f0[k].w - s0.w; sq += d * d;
            d = f1[k].x - s1.x; sq += d * d;
            d = f1[k].y - s1.y; sq += d * d;
            d = f1[k].z - s1.z; sq += d * d;
            d = f1[k].w - s1.w; sq += d * d;
            const float t = sq * inv_sigma;
            float alpha = expf(-t);
            float log_a;
            if (alpha >= 0.99f)      { alpha = 0.99f; log_a = -0.010050336f; } // ln(0.99)
            else if (alpha <= 0.01f) { alpha = 0.01f; log_a = -4.6051702f;  }  // ln(0.01)
            else                     { log_a = -t; }
            mb[s * HW + p] = ls[k] + log_a;
            ls[k] += log1pf(-alpha);
            sb[(s + 1) * HW + p] = ls[k];
        }
        // LDS race-freedom: parity double-buffer on swv/swi/sSeed + the two
        // barriers above separate same-slot accesses two steps apart.
    }

    #pragma unroll
    for (int k = 0; k < PPT; ++k) {
        const int p = base + k * NT + tid;
        mb[(K_STEPS - 1) * HW + p] = ls[k];  // last mask = final scope
    }
}

extern "C" void kernel_launch(void* const* d_in, const int* in_sizes, int n_in,
                              void* d_out, int out_size, void* d_ws, size_t ws_size,
                              hipStream_t stream) {
    const float* x          = (const float*)d_in[0];  // [32,64,128,128]
    const float* rand_pixel = (const float*)d_in[1];  // [32,1,128,128]
    const float* conv_w     = (const float*)d_in[2];  // [8,64]
    const float* conv_b     = (const float*)d_in[3];  // [8]
    const float* gate       = (const float*)d_in[4];  // scalar
    const float* log_sigma  = (const float*)d_in[5];  // scalar

    float* masks  = (float*)d_out;                          // [32,8,128,128]
    float* scopes = masks + (long long)BATCH * K_STEPS * HW;

    float* feat = (float*)d_ws;  // [32][16384][8] = 16.8 MB
    unsigned long long* flags =
        (unsigned long long*)((char*)d_ws + FEAT_BYTES);     // 14 KB

    semiconv_kernel<<<(BATCH * HW) / (256 * 4), 256, 0, stream>>>(
        x, conv_w, conv_b, gate, feat, flags);

    stick_kernel<<<BATCH * BLK_PER_B, NT, 0, stream>>>(
        feat, rand_pixel, log_sigma, masks, scopes, flags);
}